// Round 10
// baseline (883.436 us; speedup 1.0000x reference)
//
#include <hip/hip_runtime.h>
#include <hip/hip_fp16.h>
#include <math.h>

#define N_    16
#define CIN_  10
#define CB_   16
#define H_    512
#define W_    512
#define HW_   (512*512)
#define EPSF  1e-5f

// fast sigmoid: v_mul + v_exp + v_add + v_rcp (vs ~22-instr libm expf + IEEE div)
__device__ __forceinline__ float sgm(float z){
  float e = __builtin_amdgcn_exp2f(z * -1.44269504088896f);
  return __builtin_amdgcn_rcpf(1.0f + e);
}

// ---- pass 1: channel sums + pair products of x; SLOT-MAJOR partial stores ----
// v10: SPp[k*1024 + (n*64+bx)] deterministic stores (no atomics -> no k_zero).
// Block (0,0) also zeroes SB1+SB2 (768 contiguous doubles) for k_upstats'
// atomics -- stream order guarantees completion before k_upstats launches.
__global__ __launch_bounds__(256) void k_cov(
    const float* __restrict__ x, double* __restrict__ SPp, double* __restrict__ SBz)
{
  if (blockIdx.x==0 && blockIdx.y==0){
    for (int i=threadIdx.x; i<768; i+=256) SBz[i]=0.0;
  }
  const int n = blockIdx.y;
  const int base = blockIdx.x*4096;
  const float* xp = x + (size_t)n*CIN_*HW_;
  float s[CIN_], p[55];
#pragma unroll
  for (int i=0;i<CIN_;++i) s[i]=0.f;
#pragma unroll
  for (int i=0;i<55;++i) p[i]=0.f;
#pragma unroll 1
  for (int it=0; it<4; ++it){
    const int off = base + it*1024 + threadIdx.x*4;
    float4 xv[CIN_];
#pragma unroll
    for (int ci=0; ci<CIN_; ++ci)
      xv[ci] = *(const float4*)(xp + (size_t)ci*HW_ + off);
#pragma unroll
    for (int ci=0; ci<CIN_; ++ci)
      s[ci] += xv[ci].x + xv[ci].y + xv[ci].z + xv[ci].w;
    int k=0;
#pragma unroll
    for (int i=0;i<CIN_;++i)
#pragma unroll
      for (int j=i;j<CIN_;++j,++k)
        p[k] += xv[i].x*xv[j].x + xv[i].y*xv[j].y + xv[i].z*xv[j].z + xv[i].w*xv[j].w;
  }
  __shared__ float red[4][65];
  const int lane = threadIdx.x & 63, wid = threadIdx.x >> 6;
#pragma unroll
  for (int k=0;k<65;++k){
    float v = (k<CIN_) ? s[k] : p[k-CIN_];
    for (int o=32;o>0;o>>=1) v += __shfl_down(v,o);
    if (lane==0) red[wid][k]=v;
  }
  __syncthreads();
  if (threadIdx.x < 65){
    float v = red[0][threadIdx.x]+red[1][threadIdx.x]+red[2][threadIdx.x]+red[3][threadIdx.x];
    SPp[(size_t)threadIdx.x*1024 + (size_t)n*64 + blockIdx.x] = (double)v;
  }
}

// ---- finalize BN1 from SPp partials (parallel slot-major reduce); fold into W1f/b1f ----
// 256 threads = 4 waves; wave w reduces slots w, w+4, ... (1024 contiguous doubles each).
__global__ void k_fin1(const double* __restrict__ SPp, const float* __restrict__ w1,
                       const float* __restrict__ b1, const float* __restrict__ g,
                       const float* __restrict__ be,
                       float* __restrict__ W1f, float* __restrict__ b1f){
  __shared__ double Sm[CIN_], Cv[55];
  const int t = threadIdx.x, lane = t & 63, wv = t >> 6;
  for (int k = wv; k < 65; k += 4){
    double s = 0.0;
    for (int j = 0; j < 16; ++j) s += SPp[(size_t)k*1024 + lane + 64*j];
    for (int o = 32; o > 0; o >>= 1) s += __shfl_down(s, o);
    if (lane == 0){ if (k < CIN_) Sm[k] = s; else Cv[k-CIN_] = s; }
  }
  __syncthreads();
  if (t < CB_){
    const double M = 16.0*(double)HW_;
    double b = (double)b1[t];
    double wd[CIN_];
    double lin = 0.0;
    for (int i=0;i<CIN_;++i){ wd[i] = (double)w1[t*CIN_+i]; lin += wd[i]*Sm[i]/M; }
    double mean = b + lin;
    double ey2 = b*b + 2.0*b*lin;
    int k=0;
    for (int i=0;i<CIN_;++i)
      for (int j=i;j<CIN_;++j,++k)
        ey2 += (i==j ? 1.0 : 2.0) * wd[i]*wd[j]*(Cv[k]/M);
    double var = ey2 - mean*mean;
    float a = g[t]*rsqrtf((float)var + EPSF);
    float sh = be[t] - (float)mean*a;
    b1f[t] = a*b1[t] + sh;
    for (int i=0;i<CIN_;++i) W1f[t*CIN_+i] = a*w1[t*CIN_+i];
  }
}

// ---- pass 2: conv1(BN1-folded) -> sigmoid -> conv2 (1x1); write B as FP16; S2 partials ----
// Proven text (r8/r9: 145.5-146.7us, VGPR 112). Do not touch ANY text here.
__global__ __launch_bounds__(256) void k_band2(
    const float* __restrict__ x,
    const float* __restrict__ W1f, const float* __restrict__ b1f,
    const float* __restrict__ w2, const float* __restrict__ b2,
    __half* __restrict__ B, double* __restrict__ S2p)
{
  const int n = blockIdx.y;
  const int base = blockIdx.x*4096;
  const float* xp = x + (size_t)n*CIN_*HW_;
  __half* bp = B + (size_t)n*CB_*HW_;
  float sum[CB_], sq[CB_];
#pragma unroll
  for (int c=0;c<CB_;++c){ sum[c]=0.f; sq[c]=0.f; }
#pragma unroll 1
  for (int it=0; it<4; ++it){
    const int p = base + it*1024 + threadIdx.x*4;
    float4 xv[CIN_];
#pragma unroll
    for (int ci=0; ci<CIN_; ++ci)
      xv[ci] = *(const float4*)(xp + (size_t)ci*HW_ + p);
    float4 s[CB_];
#pragma unroll
    for (int co=0; co<CB_; ++co){
      float bb = b1f[co];
      float ox=bb, oy=bb, oz=bb, ow=bb;
#pragma unroll
      for (int ci=0; ci<CIN_; ++ci){
        float w = W1f[co*CIN_+ci];
        ox += w*xv[ci].x; oy += w*xv[ci].y; oz += w*xv[ci].z; ow += w*xv[ci].w;
      }
      s[co].x = sgm(ox); s[co].y = sgm(oy);
      s[co].z = sgm(oz); s[co].w = sgm(ow);
    }
#pragma unroll
    for (int co=0; co<CB_; ++co){
      float bb = b2[co];
      float ox=bb, oy=bb, oz=bb, ow=bb;
#pragma unroll
      for (int ci=0; ci<CB_; ++ci){
        float w = w2[co*CB_+ci];
        ox += w*s[ci].x; oy += w*s[ci].y; oz += w*s[ci].z; ow += w*s[ci].w;
      }
      union { __half2 h[2]; uint2 u; } cu;
      cu.h[0] = __floats2half2_rn(ox, oy);
      cu.h[1] = __floats2half2_rn(oz, ow);
      *(uint2*)(bp + (size_t)co*HW_ + p) = cu.u;
      sum[co] += ox+oy+oz+ow;
      sq[co]  += ox*ox+oy*oy+oz*oz+ow*ow;
    }
  }
  __shared__ float red[4][CB_][2];
  const int lane = threadIdx.x & 63, wid = threadIdx.x >> 6;
#pragma unroll
  for (int c=0;c<CB_;++c){
    float s=sum[c], q=sq[c];
    for (int off=32; off>0; off>>=1){ s += __shfl_down(s,off); q += __shfl_down(q,off); }
    if (lane==0){ red[wid][c][0]=s; red[wid][c][1]=q; }
  }
  __syncthreads();
  if (threadIdx.x < CB_*2){
    int c = threadIdx.x>>1, k = threadIdx.x&1;
    float t = red[0][c][k]+red[1][c][k]+red[2][c][k]+red[3][c][k];
    S2p[(((size_t)n*CB_ + c)*64 + blockIdx.x)*2 + k] = (double)t;
  }
}

// ---- pass 3: inline-AB2 (from S2p) + sum/sumsq of sigmoid(BN2(B fp16)); SVp partials ----
// v10: AB2 computed per block (tree-reduce of 1024 S2p entries for this channel)
//   -> k_finp launch removed. Output now deterministic partial stores -> no SV zeroing.
__global__ __launch_bounds__(256) void k_varstats(
    const __half* __restrict__ B, const double* __restrict__ S2p,
    const float* __restrict__ g2, const float* __restrict__ be2,
    double* __restrict__ SVp)
{
  const int n = blockIdx.z, c = blockIdx.y;
  __shared__ double rs[256], rq[256];
  __shared__ float sab[2];
  {
    double s=0.0, q=0.0;
    for (int e = threadIdx.x; e < 1024; e += 256){
      int nn = e >> 6, bb = e & 63;
      size_t idx = (((size_t)nn*CB_ + c)*64 + bb)*2;
      s += S2p[idx]; q += S2p[idx+1];
    }
    rs[threadIdx.x]=s; rq[threadIdx.x]=q; __syncthreads();
    for (int h=128; h>0; h>>=1){
      if (threadIdx.x < h){ rs[threadIdx.x]+=rs[threadIdx.x+h]; rq[threadIdx.x]+=rq[threadIdx.x+h]; }
      __syncthreads();
    }
    if (threadIdx.x==0){
      const double invM = 1.0/4194304.0;
      double mean = rs[0]*invM, var = rq[0]*invM - mean*mean;
      float a = g2[c]*rsqrtf((float)var + EPSF);
      sab[0]=a; sab[1]=be2[c] - (float)mean*a;
    }
    __syncthreads();
  }
  const float a = sab[0], b = sab[1];
  const __half* p = B + ((size_t)(n*CB_+c))*HW_ + blockIdx.x*4096;
  uint2 u0 = *(const uint2*)(p +    0 + threadIdx.x*4);
  uint2 u1 = *(const uint2*)(p + 1024 + threadIdx.x*4);
  uint2 u2 = *(const uint2*)(p + 2048 + threadIdx.x*4);
  uint2 u3 = *(const uint2*)(p + 3072 + threadIdx.x*4);
  float sum=0.f, sq=0.f;
#pragma unroll
  for (int j=0;j<4;++j){
    uint2 uu = (j==0)?u0:((j==1)?u1:((j==2)?u2:u3));
    union { uint2 u; __half2 h[2]; } cu; cu.u = uu;
    float2 f0 = __half22float2(cu.h[0]);
    float2 f1 = __half22float2(cu.h[1]);
    float e0 = sgm(a*f0.x+b), e1 = sgm(a*f0.y+b);
    float e2 = sgm(a*f1.x+b), e3 = sgm(a*f1.y+b);
    sum += e0+e1+e2+e3;
    sq  += e0*e0+e1*e1+e2*e2+e3*e3;
  }
  __shared__ float red[4][2];
  const int lane = threadIdx.x & 63, wid = threadIdx.x >> 6;
  for (int off=32; off>0; off>>=1){ sum += __shfl_down(sum,off); sq += __shfl_down(sq,off); }
  if (lane==0){ red[wid][0]=sum; red[wid][1]=sq; }
  __syncthreads();
  if (threadIdx.x < 2){
    int k = threadIdx.x;
    float t = red[0][k]+red[1][k]+red[2][k]+red[3][k];
    SVp[(((size_t)n*CB_ + c)*64 + blockIdx.x)*2 + k] = (double)t;
  }
}

// ---- conv3x3 (3->8) + maxpool2 + sigmoid; INLINE top-3 selection + AB2-for-selected ----
// v10: per-block topk from SVp (16ch x 64 partials) + AB2 via the SAME reduce
//   pattern as k_varstats (identical bits) -> k_topk launch removed.
__global__ __launch_bounds__(256) void k_conv1p(
    const __half* __restrict__ B, const double* __restrict__ SVp,
    const double* __restrict__ S2p, const float* __restrict__ g2,
    const float* __restrict__ be2,
    const float* __restrict__ w, const float* __restrict__ bias,
    float* __restrict__ X1)
{
  const int n = blockIdx.y, ho = blockIdx.x, wo = threadIdx.x;
  __shared__ double rs[256], rq[256];
  __shared__ double var[CB_];
  __shared__ int chs[3];
  __shared__ float ca[3], cb[3];
  // Phase A: per-channel unbiased variance for this n (16 ch x 16 slots x 4 partials)
  {
    int c = threadIdx.x >> 4, slot = threadIdx.x & 15;
    double s=0.0, q=0.0;
    for (int j=0;j<4;++j){
      int bb = slot*4 + j;
      size_t idx = (((size_t)n*CB_ + c)*64 + bb)*2;
      s += SVp[idx]; q += SVp[idx+1];
    }
    rs[threadIdx.x]=s; rq[threadIdx.x]=q; __syncthreads();
    for (int h=8; h>0; h>>=1){
      if (slot < h){ rs[threadIdx.x]+=rs[threadIdx.x+h]; rq[threadIdx.x]+=rq[threadIdx.x+h]; }
      __syncthreads();
    }
    if (slot==0){
      double s_=rs[threadIdx.x], q_=rq[threadIdx.x];
      const double M = (double)HW_;
      var[c] = (q_ - s_*s_/M)/(M-1.0);
    }
    __syncthreads();
    if (threadIdx.x==0){
      double v[CB_];
      for (int c2=0;c2<CB_;++c2) v[c2]=var[c2];
      for (int k=0;k<3;++k){
        int bi=0; double bv=v[0];
        for (int c2=1;c2<CB_;++c2) if (v[c2]>bv){ bv=v[c2]; bi=c2; }
        chs[k]=bi; v[bi]=-1e300;
      }
    }
    __syncthreads();
    // Phase B: AB2 for the 3 selected channels (same pattern as k_varstats => same bits)
    for (int k3=0;k3<3;++k3){
      int c2 = chs[k3];
      double s2=0.0, q2=0.0;
      for (int e = threadIdx.x; e < 1024; e += 256){
        int nn = e >> 6, bb = e & 63;
        size_t idx = (((size_t)nn*CB_ + c2)*64 + bb)*2;
        s2 += S2p[idx]; q2 += S2p[idx+1];
      }
      rs[threadIdx.x]=s2; rq[threadIdx.x]=q2; __syncthreads();
      for (int h=128; h>0; h>>=1){
        if (threadIdx.x < h){ rs[threadIdx.x]+=rs[threadIdx.x+h]; rq[threadIdx.x]+=rq[threadIdx.x+h]; }
        __syncthreads();
      }
      if (threadIdx.x==0){
        const double invM = 1.0/4194304.0;
        double mean = rs[0]*invM, vv = rq[0]*invM - mean*mean;
        float a = g2[c2]*rsqrtf((float)vv + EPSF);
        ca[k3]=a; cb[k3]=be2[c2] - (float)mean*a;
      }
      __syncthreads();
    }
  }
  __shared__ float tile[3][4][516];
#pragma unroll
  for (int k=0;k<3;++k){
    const __half* pc = B + ((size_t)(n*CB_+chs[k]))*HW_;
    const float a = ca[k], bb = cb[k];
#pragma unroll
    for (int dy=0;dy<4;++dy){
      const int r = 2*ho-1+dy;
      float tx = 0.f, ty = 0.f;
      if (r>=0 && r<H_){
        const __half2 v = *(const __half2*)(pc + (size_t)r*W_ + 2*wo);
        float2 f = __half22float2(v);
        tx = sgm(a*f.x+bb); ty = sgm(a*f.y+bb);
      }
      tile[k][dy][1+2*wo] = tx;
      tile[k][dy][2+2*wo] = ty;
    }
  }
  if (wo < 24){
    int k = wo>>3, dy = (wo&7)>>1;
    tile[k][dy][(wo&1) ? 513 : 0] = 0.f;
  }
  __syncthreads();
  float in[3][4][4];
#pragma unroll
  for (int k=0;k<3;++k)
#pragma unroll
    for (int dy=0;dy<4;++dy)
#pragma unroll
      for (int dx=0;dx<4;++dx)
        in[k][dy][dx] = tile[k][dy][2*wo+dx];
#pragma unroll
  for (int co=0;co<8;++co){
    float m = -1e30f;
#pragma unroll
    for (int py=0;py<2;++py)
#pragma unroll
    for (int px=0;px<2;++px){
      float acc = bias[co];
#pragma unroll
      for (int k=0;k<3;++k)
#pragma unroll
      for (int kh=0;kh<3;++kh)
#pragma unroll
      for (int kw=0;kw<3;++kw)
        acc += w[((co*3+k)*3+kh)*3+kw] * in[k][py+kh][px+kw];
      m = fmaxf(m, acc);
    }
    X1[((size_t)(n*8+co)*256 + ho)*256 + wo] = sgm(m);
  }
}

// ---- conv3x3 (8->16, pad1) + maxpool2 + sigmoid -> X2[16,16,128,128] ----
__global__ __launch_bounds__(256) void k_conv2p(
    const float* __restrict__ X1, const float* __restrict__ w, const float* __restrict__ bias,
    float* __restrict__ X2)
{
  const int n  = blockIdx.y;
  const int wo = threadIdx.x & 127;
  const int ho = blockIdx.x*2 + (threadIdx.x>>7);
  float acc[16][4];
#pragma unroll
  for (int co=0;co<16;++co){
    float bb = bias[co];
    acc[co][0]=bb; acc[co][1]=bb; acc[co][2]=bb; acc[co][3]=bb;
  }
#pragma unroll 1
  for (int ci=0; ci<8; ++ci){
    const float* p = X1 + ((size_t)(n*8+ci))*65536;
    float patch[4][4];
#pragma unroll
    for (int dy=0;dy<4;++dy){
      int r = 2*ho-1+dy;
      bool rok = (r>=0 && r<256);
#pragma unroll
      for (int dx=0;dx<4;++dx){
        int cc = 2*wo-1+dx;
        patch[dy][dx] = (rok && cc>=0 && cc<256) ? p[r*256+cc] : 0.f;
      }
    }
#pragma unroll
    for (int co=0;co<16;++co){
      const float* wp = w + (co*8+ci)*9;
#pragma unroll
      for (int py=0;py<2;++py)
#pragma unroll
      for (int px=0;px<2;++px){
        float a = acc[co][py*2+px];
#pragma unroll
        for (int kh=0;kh<3;++kh)
#pragma unroll
        for (int kw=0;kw<3;++kw)
          a += wp[kh*3+kw]*patch[py+kh][px+kw];
        acc[co][py*2+px] = a;
      }
    }
  }
#pragma unroll
  for (int co=0;co<16;++co){
    float m = fmaxf(fmaxf(acc[co][0],acc[co][1]), fmaxf(acc[co][2],acc[co][3]));
    X2[((size_t)(n*16+co)*128 + ho)*128 + wo] = sgm(m);
  }
}

// ---- merged stats: relu(up4(X2)) for y<16 -> SB1; relu(up2(X1)) for y>=16 -> SB2 ----
// Atomics into SB1/SB2 (zeroed by k_cov earlier in the stream).
__global__ __launch_bounds__(256) void k_upstats(
    const float* __restrict__ X2, const float* __restrict__ X1,
    double* __restrict__ SB1, double* __restrict__ SB2)
{
  const int n = blockIdx.z, y = blockIdx.y;
  const int id = blockIdx.x*256 + threadIdx.x;
  const int ho = id>>7, m = id&127;
  float sum, sq;
  if (y < 16){
    const int c = y;
    const float* p = X2 + ((size_t)(n*16+c))*16384;
    const int q = ho>>2, r = ho&3;
    int rA, rB; float wA;
    if (r==0){ rA=q-1; rB=q;   wA=0.375f; }
    else if (r==1){ rA=q-1; rB=q;   wA=0.125f; }
    else if (r==2){ rA=q;   rB=q+1; wA=0.875f; }
    else          { rA=q;   rB=q+1; wA=0.625f; }
    const float wB = 1.f-wA;
    rA = max(rA,0); rB = min(rB,127);
    const int c0 = max(m-1,0), c1 = m, c2 = min(m+1,127);
    const float* pa = p + rA*128; const float* pb = p + rB*128;
    float t0 = wA*pa[c0]+wB*pb[c0];
    float t1 = wA*pa[c1]+wB*pb[c1];
    float t2 = wA*pa[c2]+wB*pb[c2];
    float o0 = fmaxf(0.375f*t0+0.625f*t1, 0.f);
    float o1 = fmaxf(0.125f*t0+0.875f*t1, 0.f);
    float o2 = fmaxf(0.875f*t1+0.125f*t2, 0.f);
    float o3 = fmaxf(0.625f*t1+0.375f*t2, 0.f);
    sum = o0+o1+o2+o3;
    sq  = o0*o0+o1*o1+o2*o2+o3*o3;
  } else {
    const int c = y-16;
    const float* p = X1 + ((size_t)(n*8+c))*65536;
    const int i = ho>>1, r = ho&1;
    int rA, rB; float wA;
    if (r==0){ rA=i-1; rB=i;   wA=0.25f; }
    else     { rA=i;   rB=i+1; wA=0.75f; }
    const float wB = 1.f-wA;
    rA = max(rA,0); rB = min(rB,255);
    const int c0 = max(2*m-1,0), c1 = 2*m, c2 = 2*m+1, c3 = min(2*m+2,255);
    const float* pa = p + rA*256; const float* pb = p + rB*256;
    float t0 = wA*pa[c0]+wB*pb[c0];
    float t1 = wA*pa[c1]+wB*pb[c1];
    float t2 = wA*pa[c2]+wB*pb[c2];
    float t3 = wA*pa[c3]+wB*pb[c3];
    float o0 = fmaxf(0.25f*t0+0.75f*t1, 0.f);
    float o1 = fmaxf(0.75f*t1+0.25f*t2, 0.f);
    float o2 = fmaxf(0.25f*t1+0.75f*t2, 0.f);
    float o3 = fmaxf(0.75f*t2+0.25f*t3, 0.f);
    sum = o0+o1+o2+o3;
    sq  = o0*o0+o1*o1+o2*o2+o3*o3;
  }
  __shared__ float red[4][2];
  const int lane = threadIdx.x & 63, wid = threadIdx.x >> 6;
  for (int off=32; off>0; off>>=1){ sum += __shfl_down(sum,off); sq += __shfl_down(sq,off); }
  if (lane==0){ red[wid][0]=sum; red[wid][1]=sq; }
  __syncthreads();
  if (threadIdx.x < 2){
    int k = threadIdx.x;
    float t = red[0][k]+red[1][k]+red[2][k]+red[3][k];
    if (y < 16) atomicAdd(&SB1[(n*16+y)*2+k], (double)t);
    else        atomicAdd(&SB2[(n*8+(y-16))*2+k], (double)t);
  }
}

// ---- final: INLINE BN finalize (from SB1/SB2) + up2/up4 + BN + concat + 1x1 conv ----
// v10: ABB1/ABB2 computed per block (same n-loop order as old k_fin -> identical
//   bits given same SB totals) -> k_fin2 launch removed.
__global__ __launch_bounds__(256) void k_final(
    const float* __restrict__ X1, const float* __restrict__ X2,
    const double* __restrict__ SB1, const double* __restrict__ SB2,
    const float* __restrict__ g1, const float* __restrict__ be1,
    const float* __restrict__ g2, const float* __restrict__ be2,
    const float* __restrict__ w1k, const float* __restrict__ b1k,
    float* __restrict__ out)
{
  const int n = blockIdx.y, bx = blockIdx.x, tid = threadIdx.x;
  __shared__ float sA1[32];   // [a16 | b16] for X2 branch (SB1/g_bn1)
  __shared__ float sA2[16];   // [a8 | b8]  for X1 branch (SB2/g_bn2)
  if (tid < 16){
    double s=0.0,q=0.0;
    for (int nn=0;nn<N_;++nn){ s+=SB1[(nn*16+tid)*2]; q+=SB1[(nn*16+tid)*2+1]; }
    const double invM = 1.0/4194304.0;
    double mean=s*invM, vv=q*invM-mean*mean;
    float a=g1[tid]*rsqrtf((float)vv+EPSF);
    sA1[tid]=a; sA1[16+tid]=be1[tid]-(float)mean*a;
  } else if (tid < 24){
    int c = tid-16;
    double s=0.0,q=0.0;
    for (int nn=0;nn<N_;++nn){ s+=SB2[(nn*8+c)*2]; q+=SB2[(nn*8+c)*2+1]; }
    const double invM = 1.0/4194304.0;
    double mean=s*invM, vv=q*invM-mean*mean;
    float a=g2[c]*rsqrtf((float)vv+EPSF);
    sA2[c]=a; sA2[8+c]=be2[c]-(float)mean*a;
  }
  __shared__ float sx1[8][3][256];
  __shared__ float sx2[16][2][128];
  {
    const int R0 = max(bx-1,0), R1 = bx, R2 = min(bx+1,255);
#pragma unroll
    for (int pr=0; pr<24; ++pr){
      const int ch = pr/3, row = pr%3;
      const int rr = (row==0) ? R0 : ((row==1) ? R1 : R2);
      sx1[ch][row][tid] = X1[((size_t)(n*8+ch)*256 + rr)*256 + tid];
    }
  }
  {
    const int q = bx>>1;
    const int Q0 = (bx&1) ? q : max(q-1,0);
    const int Q1 = (bx&1) ? min(q+1,127) : q;
    const int col = tid & 127, half = tid >> 7;
#pragma unroll
    for (int k=0;k<16;++k){
      const int pr = half + 2*k;
      const int ch = pr>>1, row = pr&1;
      const int rr = row ? Q1 : Q0;
      sx2[ch][row][col] = X2[((size_t)(n*16+ch)*128 + rr)*128 + col];
    }
  }
  __syncthreads();

  const int h = 2*bx + (tid>>7);
  const int m = tid & 127;
  float acc[5][4];
#pragma unroll
  for (int cls=0;cls<5;++cls){
    float bb = b1k[cls];
    acc[cls][0]=bb; acc[cls][1]=bb; acc[cls][2]=bb; acc[cls][3]=bb;
  }
  {
    const int r = h&1;
    const float wA = (r==0) ? 0.25f : 0.75f;
    const float wB = 1.f-wA;
    const int paL = r, pbL = r+1;
    const int c0 = max(2*m-1,0), c1 = 2*m, c2 = 2*m+1, c3 = min(2*m+2,255);
#pragma unroll
    for (int c=0;c<8;++c){
      const float* pa = &sx1[c][paL][0];
      const float* pb = &sx1[c][pbL][0];
      float t0 = wA*pa[c0]+wB*pb[c0];
      float t1 = wA*pa[c1]+wB*pb[c1];
      float t2 = wA*pa[c2]+wB*pb[c2];
      float t3 = wA*pa[c3]+wB*pb[c3];
      float o0 = 0.25f*t0+0.75f*t1, o1 = 0.75f*t1+0.25f*t2;
      float o2 = 0.25f*t1+0.75f*t2, o3 = 0.75f*t2+0.25f*t3;
      const float a = sA2[c], bb = sA2[8+c];
      o0 = a*fmaxf(o0,0.f)+bb; o1 = a*fmaxf(o1,0.f)+bb;
      o2 = a*fmaxf(o2,0.f)+bb; o3 = a*fmaxf(o3,0.f)+bb;
#pragma unroll
      for (int cls=0;cls<5;++cls){
        float wv = w1k[cls*24+c];
        acc[cls][0]+=wv*o0; acc[cls][1]+=wv*o1; acc[cls][2]+=wv*o2; acc[cls][3]+=wv*o3;
      }
    }
  }
  {
    const int r = h&3;
    float wA;
    if (r==0)      wA=0.375f;
    else if (r==1) wA=0.125f;
    else if (r==2) wA=0.875f;
    else           wA=0.625f;
    const float wB = 1.f-wA;
    const int c0 = max(m-1,0), c1 = m, c2 = min(m+1,127);
#pragma unroll
    for (int c=0;c<16;++c){
      const float* pa = &sx2[c][0][0];
      const float* pb = &sx2[c][1][0];
      float t0 = wA*pa[c0]+wB*pb[c0];
      float t1 = wA*pa[c1]+wB*pb[c1];
      float t2 = wA*pa[c2]+wB*pb[c2];
      float o0 = 0.375f*t0+0.625f*t1;
      float o1 = 0.125f*t0+0.875f*t1;
      float o2 = 0.875f*t1+0.125f*t2;
      float o3 = 0.625f*t1+0.375f*t2;
      const float a = sA1[c], bb = sA1[16+c];
      o0 = a*fmaxf(o0,0.f)+bb; o1 = a*fmaxf(o1,0.f)+bb;
      o2 = a*fmaxf(o2,0.f)+bb; o3 = a*fmaxf(o3,0.f)+bb;
#pragma unroll
      for (int cls=0;cls<5;++cls){
        float wv = w1k[cls*24+8+c];
        acc[cls][0]+=wv*o0; acc[cls][1]+=wv*o1; acc[cls][2]+=wv*o2; acc[cls][3]+=wv*o3;
      }
    }
  }
#pragma unroll
  for (int cls=0;cls<5;++cls){
    float4 v; v.x=acc[cls][0]; v.y=acc[cls][1]; v.z=acc[cls][2]; v.w=acc[cls][3];
    *(float4*)(out + ((size_t)(n*5+cls))*HW_ + (size_t)h*W_ + 4*m) = v;
  }
}

extern "C" void kernel_launch(void* const* d_in, const int* in_sizes, int n_in,
                              void* d_out, int out_size, void* d_ws, size_t ws_size,
                              hipStream_t stream) {
  const float* x       = (const float*)d_in[0];
  const float* w_ext1  = (const float*)d_in[1];
  const float* b_ext1  = (const float*)d_in[2];
  const float* g_ebn1  = (const float*)d_in[3];
  const float* be_ebn1 = (const float*)d_in[4];
  const float* w_ext2  = (const float*)d_in[5];
  const float* b_ext2  = (const float*)d_in[6];
  const float* g_ebn2  = (const float*)d_in[7];
  const float* be_ebn2 = (const float*)d_in[8];
  const float* w_c1    = (const float*)d_in[9];
  const float* b_c1    = (const float*)d_in[10];
  const float* w_c2    = (const float*)d_in[11];
  const float* b_c2    = (const float*)d_in[12];
  const float* g_bn1   = (const float*)d_in[13];
  const float* be_bn1  = (const float*)d_in[14];
  const float* g_bn2   = (const float*)d_in[15];
  const float* be_bn2  = (const float*)d_in[16];
  const float* w_1k    = (const float*)d_in[17];
  const float* b_1k    = (const float*)d_in[18];
  float* outp = (float*)d_out;

  char* ws = (char*)d_ws;
  __half* B = (__half*)ws;                                  // [0, 134217728): fp16 B
  // free region [134217728, 268435456) (fp16 halved B):
  double* S2p = (double*)(ws + 134217728);                  // 262144 B (band2 -> varstats/conv1p)
  double* SVp = (double*)(ws + 134217728 + 262144);         // 262144 B (varstats -> conv1p)
  double* SPp = (double*)(ws + 134217728 + 524288);         // 65*1024*8 = 532480 B (cov -> fin1)
  float* X1 = (float*)(ws + 268435456);                     // 33554432 B
  float* X2 = (float*)(ws + 268435456 + 33554432);          // 16777216 B
  char*  sb = ws + 268435456 + 33554432 + 16777216;
  double* SB1 = (double*)sb;           // 512 doubles
  double* SB2 = SB1 + 512;             // 256 doubles (contiguous w/ SB1: 768 total, zeroed by k_cov)
  float*  W1f = (float*)(SB2 + 256);   // 160
  float*  b1f = W1f + 160;             // 16

  k_cov<<<dim3(64,16),256,0,stream>>>(x, SPp, SB1);
  k_fin1<<<1,256,0,stream>>>(SPp, w_ext1, b_ext1, g_ebn1, be_ebn1, W1f, b1f);
  k_band2<<<dim3(64,16),256,0,stream>>>(x, W1f, b1f, w_ext2, b_ext2, B, S2p);
  k_varstats<<<dim3(64,16,16),256,0,stream>>>(B, S2p, g_ebn2, be_ebn2, SVp);
  k_conv1p<<<dim3(256,16),256,0,stream>>>(B, SVp, S2p, g_ebn2, be_ebn2, w_c1, b_c1, X1);
  k_conv2p<<<dim3(64,16),256,0,stream>>>(X1, w_c2, b_c2, X2);
  k_upstats<<<dim3(256,24,16),256,0,stream>>>(X2, X1, SB1, SB2);
  k_final<<<dim3(256,16),256,0,stream>>>(X1, X2, SB1, SB2, g_bn1, be_bn1, g_bn2, be_bn2, w_1k, b_1k, outp);
}

// Round 11
// 733.969 us; speedup vs baseline: 1.2036x; 1.2036x over previous
//
#include <hip/hip_runtime.h>
#include <hip/hip_fp16.h>
#include <math.h>

#define N_    16
#define CIN_  10
#define CB_   16
#define H_    512
#define W_    512
#define HW_   (512*512)
#define EPSF  1e-5f

// fast sigmoid: v_mul + v_exp + v_add + v_rcp (vs ~22-instr libm expf + IEEE div)
__device__ __forceinline__ float sgm(float z){
  float e = __builtin_amdgcn_exp2f(z * -1.44269504088896f);
  return __builtin_amdgcn_rcpf(1.0f + e);
}

// ---------------- zero stats ----------------
__global__ void k_zero(double* __restrict__ p, int n){
  int i = blockIdx.x*256 + threadIdx.x;
  if (i < n) p[i] = 0.0;
}

// ---- finalize S2 from per-block partials: P[((n*16+c)*64 + b)*2 + k] ----
template<int NB, int C>
__global__ void k_finp(const double* __restrict__ P, const float* __restrict__ g,
                       const float* __restrict__ be, float* __restrict__ AB, double invM){
  __shared__ double rs[256], rq[256];
  const int t = threadIdx.x;
  const int c = t % C, slot = t / C, nslot = 256 / C;
  const int tot = N_ * NB;
  double s=0.0, q=0.0;
  for (int j = slot; j < tot; j += nslot){
    int n = j / NB, b = j - n*NB;
    size_t idx = ((size_t)((n*C + c)*NB + b))*2;
    s += P[idx]; q += P[idx+1];
  }
  rs[t]=s; rq[t]=q; __syncthreads();
  for (int h = nslot>>1; h>0; h>>=1){
    if (slot < h){ rs[t] += rs[t + h*C]; rq[t] += rq[t + h*C]; }
    __syncthreads();
  }
  if (slot == 0){
    double mean = rs[c]*invM;
    double var  = rq[c]*invM - mean*mean;
    float a = g[c]*rsqrtf((float)var + EPSF);
    AB[c]   = a;
    AB[C+c] = be[c] - (float)mean*a;
  }
}

// ---- merged finalizer for SB1 (block 0, C=16) and SB2 (block 1, C=8) ----
// Same body as the old k_fin, dispatched by blockIdx.x. One launch instead of two.
__global__ void k_fin2(const double* __restrict__ S1, const float* __restrict__ g1,
                       const float* __restrict__ be1, float* __restrict__ A1,
                       const double* __restrict__ S2, const float* __restrict__ g2,
                       const float* __restrict__ be2, float* __restrict__ A2,
                       double invM){
  const double* S = (blockIdx.x==0) ? S1 : S2;
  const float*  g = (blockIdx.x==0) ? g1 : g2;
  const float* be = (blockIdx.x==0) ? be1 : be2;
  float*       AB = (blockIdx.x==0) ? A1 : A2;
  const int     C = (blockIdx.x==0) ? 16 : 8;
  int c = threadIdx.x;
  if (c < C){
    double s=0.0,q=0.0;
    for (int n=0;n<N_;++n){ s+=S[(n*C+c)*2]; q+=S[(n*C+c)*2+1]; }
    double mean = s*invM;
    double var  = q*invM - mean*mean;
    float a = g[c]*rsqrtf((float)var + EPSF);
    AB[c]   = a;
    AB[C+c] = be[c] - (float)mean*a;
  }
}

// ---- pass 1: channel sums + pair products of x (BN1 stats in closed form) ----
__global__ __launch_bounds__(256) void k_cov(
    const float* __restrict__ x, double* __restrict__ SP)
{
  const int n = blockIdx.y;
  const int base = blockIdx.x*4096;
  const float* xp = x + (size_t)n*CIN_*HW_;
  float s[CIN_], p[55];
#pragma unroll
  for (int i=0;i<CIN_;++i) s[i]=0.f;
#pragma unroll
  for (int i=0;i<55;++i) p[i]=0.f;
#pragma unroll 1
  for (int it=0; it<4; ++it){
    const int off = base + it*1024 + threadIdx.x*4;
    float4 xv[CIN_];
#pragma unroll
    for (int ci=0; ci<CIN_; ++ci)
      xv[ci] = *(const float4*)(xp + (size_t)ci*HW_ + off);
#pragma unroll
    for (int ci=0; ci<CIN_; ++ci)
      s[ci] += xv[ci].x + xv[ci].y + xv[ci].z + xv[ci].w;
    int k=0;
#pragma unroll
    for (int i=0;i<CIN_;++i)
#pragma unroll
      for (int j=i;j<CIN_;++j,++k)
        p[k] += xv[i].x*xv[j].x + xv[i].y*xv[j].y + xv[i].z*xv[j].z + xv[i].w*xv[j].w;
  }
  __shared__ float red[4][65];
  const int lane = threadIdx.x & 63, wid = threadIdx.x >> 6;
#pragma unroll
  for (int k=0;k<65;++k){
    float v = (k<CIN_) ? s[k] : p[k-CIN_];
    for (int o=32;o>0;o>>=1) v += __shfl_down(v,o);
    if (lane==0) red[wid][k]=v;
  }
  __syncthreads();
  if (threadIdx.x < 65){
    float v = red[0][threadIdx.x]+red[1][threadIdx.x]+red[2][threadIdx.x]+red[3][threadIdx.x];
    atomicAdd(&SP[n*65+threadIdx.x], (double)v);
  }
}

// ---- finalize BN1 from covariance; fold BN1 into conv1 weights ----
// NOTE: must run with >= 65 threads (65 reduction slots). Launch with 128.
__global__ void k_fin1(const double* __restrict__ SP, const float* __restrict__ w1,
                       const float* __restrict__ b1, const float* __restrict__ g,
                       const float* __restrict__ be, float* __restrict__ AB,
                       float* __restrict__ W1f, float* __restrict__ b1f){
  __shared__ double Sm[CIN_], Cv[55];
  int t = threadIdx.x;
  if (t < 65){
    double s = 0.0;
    for (int n=0;n<N_;++n) s += SP[n*65+t];
    if (t < CIN_) Sm[t] = s; else Cv[t-CIN_] = s;
  }
  __syncthreads();
  if (t < CB_){
    const double M = 16.0*(double)HW_;
    double b = (double)b1[t];
    double wd[CIN_];
    double lin = 0.0;
    for (int i=0;i<CIN_;++i){ wd[i] = (double)w1[t*CIN_+i]; lin += wd[i]*Sm[i]/M; }
    double mean = b + lin;
    double ey2 = b*b + 2.0*b*lin;
    int k=0;
    for (int i=0;i<CIN_;++i)
      for (int j=i;j<CIN_;++j,++k)
        ey2 += (i==j ? 1.0 : 2.0) * wd[i]*wd[j]*(Cv[k]/M);
    double var = ey2 - mean*mean;
    float a = g[t]*rsqrtf((float)var + EPSF);
    float sh = be[t] - (float)mean*a;
    AB[t] = a;
    AB[CB_+t] = sh;
    b1f[t] = a*b1[t] + sh;
    for (int i=0;i<CIN_;++i) W1f[t*CIN_+i] = a*w1[t*CIN_+i];
  }
}

// ---- pass 2: conv1(BN1-folded) -> sigmoid -> conv2 (1x1); write B as FP16; S2 partials ----
// Proven text (r8: 145.5-145.9us, VGPR 112). S2 stats from FP32 values BEFORE
// fp16 conversion -> AB2 bitwise-identical to the fp32-B pipeline. Do not touch.
__global__ __launch_bounds__(256) void k_band2(
    const float* __restrict__ x,
    const float* __restrict__ W1f, const float* __restrict__ b1f,
    const float* __restrict__ w2, const float* __restrict__ b2,
    __half* __restrict__ B, double* __restrict__ S2p)
{
  const int n = blockIdx.y;
  const int base = blockIdx.x*4096;
  const float* xp = x + (size_t)n*CIN_*HW_;
  __half* bp = B + (size_t)n*CB_*HW_;
  float sum[CB_], sq[CB_];
#pragma unroll
  for (int c=0;c<CB_;++c){ sum[c]=0.f; sq[c]=0.f; }
#pragma unroll 1
  for (int it=0; it<4; ++it){
    const int p = base + it*1024 + threadIdx.x*4;
    float4 xv[CIN_];
#pragma unroll
    for (int ci=0; ci<CIN_; ++ci)
      xv[ci] = *(const float4*)(xp + (size_t)ci*HW_ + p);
    float4 s[CB_];
#pragma unroll
    for (int co=0; co<CB_; ++co){
      float bb = b1f[co];
      float ox=bb, oy=bb, oz=bb, ow=bb;
#pragma unroll
      for (int ci=0; ci<CIN_; ++ci){
        float w = W1f[co*CIN_+ci];
        ox += w*xv[ci].x; oy += w*xv[ci].y; oz += w*xv[ci].z; ow += w*xv[ci].w;
      }
      s[co].x = sgm(ox); s[co].y = sgm(oy);
      s[co].z = sgm(oz); s[co].w = sgm(ow);
    }
#pragma unroll
    for (int co=0; co<CB_; ++co){
      float bb = b2[co];
      float ox=bb, oy=bb, oz=bb, ow=bb;
#pragma unroll
      for (int ci=0; ci<CB_; ++ci){
        float w = w2[co*CB_+ci];
        ox += w*s[ci].x; oy += w*s[ci].y; oz += w*s[ci].z; ow += w*s[ci].w;
      }
      union { __half2 h[2]; uint2 u; } cu;
      cu.h[0] = __floats2half2_rn(ox, oy);
      cu.h[1] = __floats2half2_rn(oz, ow);
      *(uint2*)(bp + (size_t)co*HW_ + p) = cu.u;
      sum[co] += ox+oy+oz+ow;
      sq[co]  += ox*ox+oy*oy+oz*oz+ow*ow;
    }
  }
  __shared__ float red[4][CB_][2];
  const int lane = threadIdx.x & 63, wid = threadIdx.x >> 6;
#pragma unroll
  for (int c=0;c<CB_;++c){
    float s=sum[c], q=sq[c];
    for (int off=32; off>0; off>>=1){ s += __shfl_down(s,off); q += __shfl_down(q,off); }
    if (lane==0){ red[wid][c][0]=s; red[wid][c][1]=q; }
  }
  __syncthreads();
  if (threadIdx.x < CB_*2){
    int c = threadIdx.x>>1, k = threadIdx.x&1;
    float t = red[0][c][k]+red[1][c][k]+red[2][c][k]+red[3][c][k];
    S2p[(((size_t)n*CB_ + c)*64 + blockIdx.x)*2 + k] = (double)t;
  }
}

// ---- pass 3 (stats only): per-(n,c) sum/sumsq of sigmoid(BN2(B fp16)) ----
__global__ __launch_bounds__(256) void k_varstats(
    const __half* __restrict__ B, const float* __restrict__ AB2, double* __restrict__ SV)
{
  const int n = blockIdx.z, c = blockIdx.y;
  const float a = AB2[c], b = AB2[CB_+c];
  const __half* p = B + ((size_t)(n*CB_+c))*HW_ + blockIdx.x*4096;
  uint2 u0 = *(const uint2*)(p +    0 + threadIdx.x*4);
  uint2 u1 = *(const uint2*)(p + 1024 + threadIdx.x*4);
  uint2 u2 = *(const uint2*)(p + 2048 + threadIdx.x*4);
  uint2 u3 = *(const uint2*)(p + 3072 + threadIdx.x*4);
  float sum=0.f, sq=0.f;
#pragma unroll
  for (int j=0;j<4;++j){
    uint2 uu = (j==0)?u0:((j==1)?u1:((j==2)?u2:u3));
    union { uint2 u; __half2 h[2]; } cu; cu.u = uu;
    float2 f0 = __half22float2(cu.h[0]);
    float2 f1 = __half22float2(cu.h[1]);
    float e0 = sgm(a*f0.x+b), e1 = sgm(a*f0.y+b);
    float e2 = sgm(a*f1.x+b), e3 = sgm(a*f1.y+b);
    sum += e0+e1+e2+e3;
    sq  += e0*e0+e1*e1+e2*e2+e3*e3;
  }
  __shared__ float red[4][2];
  const int lane = threadIdx.x & 63, wid = threadIdx.x >> 6;
  for (int off=32; off>0; off>>=1){ sum += __shfl_down(sum,off); sq += __shfl_down(sq,off); }
  if (lane==0){ red[wid][0]=sum; red[wid][1]=sq; }
  __syncthreads();
  if (threadIdx.x < 2){
    int k = threadIdx.x;
    float t = red[0][k]+red[1][k]+red[2][k]+red[3][k];
    atomicAdd(&SV[(n*CB_+c)*2+k], (double)t);
  }
}

// ---- top-3 per-sample channels by unbiased variance (stable ties: lowest idx) ----
__global__ void k_topk(const double* __restrict__ SV, int* __restrict__ IDX){
  __shared__ double var[N_][CB_];
  int t = threadIdx.x;
  if (t < N_*CB_){
    int n=t>>4, c=t&15;
    double s=SV[t*2], q=SV[t*2+1];
    const double M = (double)HW_;
    var[n][c] = (q - s*s/M)/(M-1.0);
  }
  __syncthreads();
  if (t < N_){
    double v[CB_];
#pragma unroll
    for (int c=0;c<CB_;++c) v[c]=var[t][c];
    for (int k=0;k<3;++k){
      int bi=0; double bv=v[0];
#pragma unroll
      for (int c=1;c<CB_;++c) if (v[c]>bv){ bv=v[c]; bi=c; }
      IDX[t*3+k]=bi; v[bi]=-1e300;
    }
  }
}

// ---- conv3x3 (3->8, pad1) + maxpool2 + sigmoid; BN2+sigmoid inline on fp16 load ----
__global__ __launch_bounds__(256) void k_conv1p(
    const __half* __restrict__ B, const int* __restrict__ IDX, const float* __restrict__ AB2,
    const float* __restrict__ w, const float* __restrict__ bias,
    float* __restrict__ X1)
{
  const int n = blockIdx.y, ho = blockIdx.x, wo = threadIdx.x;
  __shared__ float tile[3][4][516];
  __shared__ int chs[3];
  __shared__ float ca[3], cb[3];
  if (threadIdx.x < 3){
    int c = IDX[n*3+threadIdx.x];
    chs[threadIdx.x] = c;
    ca[threadIdx.x] = AB2[c];
    cb[threadIdx.x] = AB2[CB_+c];
  }
  __syncthreads();
#pragma unroll
  for (int k=0;k<3;++k){
    const __half* pc = B + ((size_t)(n*CB_+chs[k]))*HW_;
    const float a = ca[k], bb = cb[k];
#pragma unroll
    for (int dy=0;dy<4;++dy){
      const int r = 2*ho-1+dy;
      float tx = 0.f, ty = 0.f;
      if (r>=0 && r<H_){
        const __half2 v = *(const __half2*)(pc + (size_t)r*W_ + 2*wo);
        float2 f = __half22float2(v);
        tx = sgm(a*f.x+bb); ty = sgm(a*f.y+bb);
      }
      tile[k][dy][1+2*wo] = tx;
      tile[k][dy][2+2*wo] = ty;
    }
  }
  if (wo < 24){
    int k = wo>>3, dy = (wo&7)>>1;
    tile[k][dy][(wo&1) ? 513 : 0] = 0.f;
  }
  __syncthreads();
  float in[3][4][4];
#pragma unroll
  for (int k=0;k<3;++k)
#pragma unroll
    for (int dy=0;dy<4;++dy)
#pragma unroll
      for (int dx=0;dx<4;++dx)
        in[k][dy][dx] = tile[k][dy][2*wo+dx];
#pragma unroll
  for (int co=0;co<8;++co){
    float m = -1e30f;
#pragma unroll
    for (int py=0;py<2;++py)
#pragma unroll
    for (int px=0;px<2;++px){
      float acc = bias[co];
#pragma unroll
      for (int k=0;k<3;++k)
#pragma unroll
      for (int kh=0;kh<3;++kh)
#pragma unroll
      for (int kw=0;kw<3;++kw)
        acc += w[((co*3+k)*3+kh)*3+kw] * in[k][py+kh][px+kw];
      m = fmaxf(m, acc);
    }
    X1[((size_t)(n*8+co)*256 + ho)*256 + wo] = sgm(m);
  }
}

// ---- conv3x3 (8->16, pad1) + maxpool2 + sigmoid -> X2[16,16,128,128] ----
__global__ __launch_bounds__(256) void k_conv2p(
    const float* __restrict__ X1, const float* __restrict__ w, const float* __restrict__ bias,
    float* __restrict__ X2)
{
  const int n  = blockIdx.y;
  const int wo = threadIdx.x & 127;
  const int ho = blockIdx.x*2 + (threadIdx.x>>7);
  float acc[16][4];
#pragma unroll
  for (int co=0;co<16;++co){
    float bb = bias[co];
    acc[co][0]=bb; acc[co][1]=bb; acc[co][2]=bb; acc[co][3]=bb;
  }
#pragma unroll 1
  for (int ci=0; ci<8; ++ci){
    const float* p = X1 + ((size_t)(n*8+ci))*65536;
    float patch[4][4];
#pragma unroll
    for (int dy=0;dy<4;++dy){
      int r = 2*ho-1+dy;
      bool rok = (r>=0 && r<256);
#pragma unroll
      for (int dx=0;dx<4;++dx){
        int cc = 2*wo-1+dx;
        patch[dy][dx] = (rok && cc>=0 && cc<256) ? p[r*256+cc] : 0.f;
      }
    }
#pragma unroll
    for (int co=0;co<16;++co){
      const float* wp = w + (co*8+ci)*9;
#pragma unroll
      for (int py=0;py<2;++py)
#pragma unroll
      for (int px=0;px<2;++px){
        float a = acc[co][py*2+px];
#pragma unroll
        for (int kh=0;kh<3;++kh)
#pragma unroll
        for (int kw=0;kw<3;++kw)
          a += wp[kh*3+kw]*patch[py+kh][px+kw];
        acc[co][py*2+px] = a;
      }
    }
  }
#pragma unroll
  for (int co=0;co<16;++co){
    float m = fmaxf(fmaxf(acc[co][0],acc[co][1]), fmaxf(acc[co][2],acc[co][3]));
    X2[((size_t)(n*16+co)*128 + ho)*128 + wo] = sgm(m);
  }
}

// ---- merged stats: relu(up4(X2)) for y<16 -> SB1; relu(up2(X1)) for y>=16 -> SB2 ----
// Bodies byte-identical to the old k_stats_up4 / k_stats_up2; one launch.
__global__ __launch_bounds__(256) void k_upstats(
    const float* __restrict__ X2, const float* __restrict__ X1,
    double* __restrict__ SB1, double* __restrict__ SB2)
{
  const int n = blockIdx.z, y = blockIdx.y;
  const int id = blockIdx.x*256 + threadIdx.x;
  const int ho = id>>7, m = id&127;
  float sum, sq;
  if (y < 16){
    const int c = y;
    const float* p = X2 + ((size_t)(n*16+c))*16384;
    const int q = ho>>2, r = ho&3;
    int rA, rB; float wA;
    if (r==0){ rA=q-1; rB=q;   wA=0.375f; }
    else if (r==1){ rA=q-1; rB=q;   wA=0.125f; }
    else if (r==2){ rA=q;   rB=q+1; wA=0.875f; }
    else          { rA=q;   rB=q+1; wA=0.625f; }
    const float wB = 1.f-wA;
    rA = max(rA,0); rB = min(rB,127);
    const int c0 = max(m-1,0), c1 = m, c2 = min(m+1,127);
    const float* pa = p + rA*128; const float* pb = p + rB*128;
    float t0 = wA*pa[c0]+wB*pb[c0];
    float t1 = wA*pa[c1]+wB*pb[c1];
    float t2 = wA*pa[c2]+wB*pb[c2];
    float o0 = fmaxf(0.375f*t0+0.625f*t1, 0.f);
    float o1 = fmaxf(0.125f*t0+0.875f*t1, 0.f);
    float o2 = fmaxf(0.875f*t1+0.125f*t2, 0.f);
    float o3 = fmaxf(0.625f*t1+0.375f*t2, 0.f);
    sum = o0+o1+o2+o3;
    sq  = o0*o0+o1*o1+o2*o2+o3*o3;
  } else {
    const int c = y-16;
    const float* p = X1 + ((size_t)(n*8+c))*65536;
    const int i = ho>>1, r = ho&1;
    int rA, rB; float wA;
    if (r==0){ rA=i-1; rB=i;   wA=0.25f; }
    else     { rA=i;   rB=i+1; wA=0.75f; }
    const float wB = 1.f-wA;
    rA = max(rA,0); rB = min(rB,255);
    const int c0 = max(2*m-1,0), c1 = 2*m, c2 = 2*m+1, c3 = min(2*m+2,255);
    const float* pa = p + rA*256; const float* pb = p + rB*256;
    float t0 = wA*pa[c0]+wB*pb[c0];
    float t1 = wA*pa[c1]+wB*pb[c1];
    float t2 = wA*pa[c2]+wB*pb[c2];
    float t3 = wA*pa[c3]+wB*pb[c3];
    float o0 = fmaxf(0.25f*t0+0.75f*t1, 0.f);
    float o1 = fmaxf(0.75f*t1+0.25f*t2, 0.f);
    float o2 = fmaxf(0.25f*t1+0.75f*t2, 0.f);
    float o3 = fmaxf(0.75f*t2+0.25f*t3, 0.f);
    sum = o0+o1+o2+o3;
    sq  = o0*o0+o1*o1+o2*o2+o3*o3;
  }
  __shared__ float red[4][2];
  const int lane = threadIdx.x & 63, wid = threadIdx.x >> 6;
  for (int off=32; off>0; off>>=1){ sum += __shfl_down(sum,off); sq += __shfl_down(sq,off); }
  if (lane==0){ red[wid][0]=sum; red[wid][1]=sq; }
  __syncthreads();
  if (threadIdx.x < 2){
    int k = threadIdx.x;
    float t = red[0][k]+red[1][k]+red[2][k]+red[3][k];
    if (y < 16) atomicAdd(&SB1[(n*16+y)*2+k], (double)t);
    else        atomicAdd(&SB2[(n*8+(y-16))*2+k], (double)t);
  }
}

// ---- final: on-the-fly up2/up4 + relu + BN + concat + 1x1 conv (24->5) ----
__global__ __launch_bounds__(256) void k_final(
    const float* __restrict__ X1, const float* __restrict__ X2,
    const float* __restrict__ ABB1, const float* __restrict__ ABB2,
    const float* __restrict__ w1k, const float* __restrict__ b1k,
    float* __restrict__ out)
{
  const int n = blockIdx.y, bx = blockIdx.x, tid = threadIdx.x;
  __shared__ float sx1[8][3][256];
  __shared__ float sx2[16][2][128];
  {
    const int R0 = max(bx-1,0), R1 = bx, R2 = min(bx+1,255);
#pragma unroll
    for (int pr=0; pr<24; ++pr){
      const int ch = pr/3, row = pr%3;
      const int rr = (row==0) ? R0 : ((row==1) ? R1 : R2);
      sx1[ch][row][tid] = X1[((size_t)(n*8+ch)*256 + rr)*256 + tid];
    }
  }
  {
    const int q = bx>>1;
    const int Q0 = (bx&1) ? q : max(q-1,0);
    const int Q1 = (bx&1) ? min(q+1,127) : q;
    const int col = tid & 127, half = tid >> 7;
#pragma unroll
    for (int k=0;k<16;++k){
      const int pr = half + 2*k;
      const int ch = pr>>1, row = pr&1;
      const int rr = row ? Q1 : Q0;
      sx2[ch][row][col] = X2[((size_t)(n*16+ch)*128 + rr)*128 + col];
    }
  }
  __syncthreads();

  const int h = 2*bx + (tid>>7);
  const int m = tid & 127;
  float acc[5][4];
#pragma unroll
  for (int cls=0;cls<5;++cls){
    float bb = b1k[cls];
    acc[cls][0]=bb; acc[cls][1]=bb; acc[cls][2]=bb; acc[cls][3]=bb;
  }
  {
    const int r = h&1;
    const float wA = (r==0) ? 0.25f : 0.75f;
    const float wB = 1.f-wA;
    const int paL = r, pbL = r+1;
    const int c0 = max(2*m-1,0), c1 = 2*m, c2 = 2*m+1, c3 = min(2*m+2,255);
#pragma unroll
    for (int c=0;c<8;++c){
      const float* pa = &sx1[c][paL][0];
      const float* pb = &sx1[c][pbL][0];
      float t0 = wA*pa[c0]+wB*pb[c0];
      float t1 = wA*pa[c1]+wB*pb[c1];
      float t2 = wA*pa[c2]+wB*pb[c2];
      float t3 = wA*pa[c3]+wB*pb[c3];
      float o0 = 0.25f*t0+0.75f*t1, o1 = 0.75f*t1+0.25f*t2;
      float o2 = 0.25f*t1+0.75f*t2, o3 = 0.75f*t2+0.25f*t3;
      const float a = ABB2[c], bb = ABB2[8+c];
      o0 = a*fmaxf(o0,0.f)+bb; o1 = a*fmaxf(o1,0.f)+bb;
      o2 = a*fmaxf(o2,0.f)+bb; o3 = a*fmaxf(o3,0.f)+bb;
#pragma unroll
      for (int cls=0;cls<5;++cls){
        float wv = w1k[cls*24+c];
        acc[cls][0]+=wv*o0; acc[cls][1]+=wv*o1; acc[cls][2]+=wv*o2; acc[cls][3]+=wv*o3;
      }
    }
  }
  {
    const int r = h&3;
    float wA;
    if (r==0)      wA=0.375f;
    else if (r==1) wA=0.125f;
    else if (r==2) wA=0.875f;
    else           wA=0.625f;
    const float wB = 1.f-wA;
    const int c0 = max(m-1,0), c1 = m, c2 = min(m+1,127);
#pragma unroll
    for (int c=0;c<16;++c){
      const float* pa = &sx2[c][0][0];
      const float* pb = &sx2[c][1][0];
      float t0 = wA*pa[c0]+wB*pb[c0];
      float t1 = wA*pa[c1]+wB*pb[c1];
      float t2 = wA*pa[c2]+wB*pb[c2];
      float o0 = 0.375f*t0+0.625f*t1;
      float o1 = 0.125f*t0+0.875f*t1;
      float o2 = 0.875f*t1+0.125f*t2;
      float o3 = 0.625f*t1+0.375f*t2;
      const float a = ABB1[c], bb = ABB1[16+c];
      o0 = a*fmaxf(o0,0.f)+bb; o1 = a*fmaxf(o1,0.f)+bb;
      o2 = a*fmaxf(o2,0.f)+bb; o3 = a*fmaxf(o3,0.f)+bb;
#pragma unroll
      for (int cls=0;cls<5;++cls){
        float wv = w1k[cls*24+8+c];
        acc[cls][0]+=wv*o0; acc[cls][1]+=wv*o1; acc[cls][2]+=wv*o2; acc[cls][3]+=wv*o3;
      }
    }
  }
#pragma unroll
  for (int cls=0;cls<5;++cls){
    float4 v; v.x=acc[cls][0]; v.y=acc[cls][1]; v.z=acc[cls][2]; v.w=acc[cls][3];
    *(float4*)(out + ((size_t)(n*5+cls))*HW_ + (size_t)h*W_ + 4*m) = v;
  }
}

extern "C" void kernel_launch(void* const* d_in, const int* in_sizes, int n_in,
                              void* d_out, int out_size, void* d_ws, size_t ws_size,
                              hipStream_t stream) {
  const float* x       = (const float*)d_in[0];
  const float* w_ext1  = (const float*)d_in[1];
  const float* b_ext1  = (const float*)d_in[2];
  const float* g_ebn1  = (const float*)d_in[3];
  const float* be_ebn1 = (const float*)d_in[4];
  const float* w_ext2  = (const float*)d_in[5];
  const float* b_ext2  = (const float*)d_in[6];
  const float* g_ebn2  = (const float*)d_in[7];
  const float* be_ebn2 = (const float*)d_in[8];
  const float* w_c1    = (const float*)d_in[9];
  const float* b_c1    = (const float*)d_in[10];
  const float* w_c2    = (const float*)d_in[11];
  const float* b_c2    = (const float*)d_in[12];
  const float* g_bn1   = (const float*)d_in[13];
  const float* be_bn1  = (const float*)d_in[14];
  const float* g_bn2   = (const float*)d_in[15];
  const float* be_bn2  = (const float*)d_in[16];
  const float* w_1k    = (const float*)d_in[17];
  const float* b_1k    = (const float*)d_in[18];
  float* outp = (float*)d_out;

  char* ws = (char*)d_ws;
  __half* B = (__half*)ws;                                  // 16*16*HW*2 = 134217728 B
  float* X1 = (float*)(ws + 268435456);                     // 33554432 B (offsets kept)
  float* X2 = (float*)(ws + 268435456 + 33554432);          // 16777216 B
  // S2 partials in the X1 region (written by k_band2, consumed by k_finp
  // before k_conv1p writes X1): 16*16*64*2 doubles = 262144 B.
  double* S2p = (double*)(ws + 268435456);
  char*  sb = ws + 268435456 + 33554432 + 16777216;
  double* SP  = (double*)sb;        // 16*65 = 1040
  double* SV  = SP  + 1040;         // 512
  double* SB1 = SV  + 512;          // 512
  double* SB2 = SB1 + 512;          // 256
  float*  AB1  = (float*)(SB2 + 256);  // 32
  float*  AB2  = AB1 + 32;             // 32
  float*  ABB1 = AB2 + 32;             // 32
  float*  ABB2 = ABB1 + 32;            // 16
  float*  W1f  = ABB2 + 16;            // 160
  float*  b1f  = W1f + 160;            // 16
  int*    IDX  = (int*)(b1f + 16);     // 48

  const double invM_bn = 1.0/4194304.0;   // N*H*W per channel

  k_zero<<<10,256,0,stream>>>(SP, 2320);   // SP+SV+SB1+SB2 (contiguous)
  k_cov<<<dim3(64,16),256,0,stream>>>(x, SP);
  k_fin1<<<1,128,0,stream>>>(SP, w_ext1, b_ext1, g_ebn1, be_ebn1, AB1, W1f, b1f);
  k_band2<<<dim3(64,16),256,0,stream>>>(x, W1f, b1f, w_ext2, b_ext2, B, S2p);
  k_finp<64,16><<<1,256,0,stream>>>(S2p, g_ebn2, be_ebn2, AB2, invM_bn);
  k_varstats<<<dim3(64,16,16),256,0,stream>>>(B, AB2, SV);
  k_topk<<<1,256,0,stream>>>(SV, IDX);
  k_conv1p<<<dim3(256,16),256,0,stream>>>(B, IDX, AB2, w_c1, b_c1, X1);
  k_conv2p<<<dim3(64,16),256,0,stream>>>(X1, w_c2, b_c2, X2);
  k_upstats<<<dim3(256,24,16),256,0,stream>>>(X2, X1, SB1, SB2);
  k_fin2<<<2,64,0,stream>>>(SB1, g_bn1, be_bn1, ABB1, SB2, g_bn2, be_bn2, ABB2, invM_bn);
  k_final<<<dim3(256,16),256,0,stream>>>(X1, X2, ABB1, ABB2, w_1k, b_1k, outp);
}